// Round 2
// baseline (312.840 us; speedup 1.0000x reference)
//
#include <hip/hip_runtime.h>

// HashEmbeddingBag mean-pool: out[b,d] = (1/max(len_b,1)) * sum_{l<len_b} weight[idx[b,l], d]
// weight: [1_000_000, 64] f32, idx: [4096, 200] i32, lengths: [4096] i32, out: [4096, 64] f32.
//
// One wave per bag. Wave splits into two 32-lane halves; each half reads one
// row per load instruction as float2 (512 B / 2 rows per VMEM instr).
// Epilogue: shfl(lane^32) cross-half add, lanes 0-31 store float2.

#define NUM_BUCKETS 1000000
#define DIM 64
#define BAGS 4096
#define LMAX 200

__global__ __launch_bounds__(64, 8) void hashbag_kernel(
    const float* __restrict__ weight,
    const int* __restrict__ idx,
    const int* __restrict__ lengths,
    float* __restrict__ out)
{
    __shared__ int s_off[LMAX];            // element offsets (idx*64), one bag per block
    const int b     = blockIdx.x;
    const int lane  = threadIdx.x;         // 0..63
    const int half  = lane >> 5;           // 0: even rows, 1: odd rows
    const int dpair = (lane & 31) << 1;    // this lane owns dims {dpair, dpair+1}
    const int len   = lengths[b];

    // Stage this bag's indices -> LDS as pre-shifted element offsets (coalesced i32 loads).
    const int* bag = idx + (long)b * LMAX;
    for (int l = lane; l < len; l += 64) {
        s_off[l] = bag[l] << 6;            // idx * DIM
    }
    __syncthreads();                       // single-wave block: compiles to a waitcnt

    const float* wbase = weight + dpair;
    float sx = 0.f, sy = 0.f;

    int l = 0;
    const int pair_end = len & ~1;
    // 8 independent float2 loads in flight = 16 rows / 4KB per iteration.
    for (; l + 16 <= pair_end; l += 16) {
        const int o0 = s_off[l +  0 + half];
        const int o1 = s_off[l +  2 + half];
        const int o2 = s_off[l +  4 + half];
        const int o3 = s_off[l +  6 + half];
        const int o4 = s_off[l +  8 + half];
        const int o5 = s_off[l + 10 + half];
        const int o6 = s_off[l + 12 + half];
        const int o7 = s_off[l + 14 + half];
        const float2 v0 = *(const float2*)(wbase + o0);
        const float2 v1 = *(const float2*)(wbase + o1);
        const float2 v2 = *(const float2*)(wbase + o2);
        const float2 v3 = *(const float2*)(wbase + o3);
        const float2 v4 = *(const float2*)(wbase + o4);
        const float2 v5 = *(const float2*)(wbase + o5);
        const float2 v6 = *(const float2*)(wbase + o6);
        const float2 v7 = *(const float2*)(wbase + o7);
        sx += ((v0.x + v1.x) + (v2.x + v3.x)) + ((v4.x + v5.x) + (v6.x + v7.x));
        sy += ((v0.y + v1.y) + (v2.y + v3.y)) + ((v4.y + v5.y) + (v6.y + v7.y));
    }
    for (; l < pair_end; l += 2) {
        const float2 v = *(const float2*)(wbase + s_off[l + half]);
        sx += v.x;
        sy += v.y;
    }
    if ((len & 1) && half == 0) {          // odd tail row: lanes 0-31 only
        const float2 v = *(const float2*)(wbase + s_off[len - 1]);
        sx += v.x;
        sy += v.y;
    }

    // Combine the two 32-lane halves: each lane adds its partner's partial.
    sx += __shfl(sx, lane ^ 32);
    sy += __shfl(sy, lane ^ 32);

    const float inv = 1.f / (float)((len > 0) ? len : 1);
    if (half == 0) {
        float2 r; r.x = sx * inv; r.y = sy * inv;
        *(float2*)(out + b * DIM + dpair) = r;   // coalesced 256B store
    }
}

extern "C" void kernel_launch(void* const* d_in, const int* in_sizes, int n_in,
                              void* d_out, int out_size, void* d_ws, size_t ws_size,
                              hipStream_t stream) {
    const float* weight  = (const float*)d_in[0];
    const int*   idx     = (const int*)d_in[1];
    const int*   lengths = (const int*)d_in[2];
    float*       out     = (float*)d_out;

    hashbag_kernel<<<BAGS, 64, 0, stream>>>(weight, idx, lengths, out);
}

// Round 4
// 308.801 us; speedup vs baseline: 1.0131x; 1.0131x over previous
//
#include <hip/hip_runtime.h>

// HashEmbeddingBag mean-pool: out[b,d] = (1/max(len_b,1)) * sum_{l<len_b} weight[idx[b,l], d]
// weight: [1_000_000, 64] f32, idx: [4096, 200] i32, lengths: [4096] i32, out: [4096, 64] f32.
//
// 128-thread block (2 waves) per bag. Each wave owns half the bag's rows.
// Within a wave: 4 groups of 16 lanes; group g fetches row r+g as float4
// (16 lanes x 16B = one 256B row; 4 rows = 1KB per VMEM instruction).
// Reduce: shfl_xor(16), shfl_xor(32) across groups; LDS combine across waves.
// Grid = 4096 blocks x 2 waves = 32 waves/CU (HW max occupancy).

#define NUM_BUCKETS 1000000
#define DIM 64
#define BAGS 4096
#define LMAX 200

__global__ __launch_bounds__(128, 8) void hashbag_kernel(
    const float* __restrict__ weight,
    const int* __restrict__ idx,
    const int* __restrict__ lengths,
    float* __restrict__ out)
{
    __shared__ int    s_off[LMAX];     // element offsets (idx*64)
    __shared__ float4 s_part[16];      // wave-1 partials

    const int b    = blockIdx.x;
    const int tid  = threadIdx.x;      // 0..127
    const int wave = tid >> 6;         // 0 or 1
    const int lane = tid & 63;
    const int g    = lane >> 4;        // row group 0..3
    const int l16  = lane & 15;        // dim group: dims [l16*4 .. l16*4+3]
    const int len  = lengths[b];

    // Stage indices -> LDS as pre-shifted element offsets (coalesced i32 loads).
    const int* bag = idx + (long)b * LMAX;
    for (int l = tid; l < len; l += 128) {
        s_off[l] = bag[l] << 6;        // idx * DIM
    }
    __syncthreads();

    // This wave's contiguous row range: wave 0 -> [0,hl), wave 1 -> [hl,len).
    const int hl    = (len + 1) >> 1;
    const int start = wave * hl;
    const int end   = (len < start + hl) ? len : (start + hl);

    const float* wbase = weight + (l16 << 2);
    float ax = 0.f, ay = 0.f, az = 0.f, aw = 0.f;

    int r = start + g;                 // group g handles rows start+g, +4, +8, ...
    // Unrolled: 4 independent 1KB row-quad loads in flight (16 rows / 4KB per iter).
    for (; r + 12 < end; r += 16) {
        const int o0 = s_off[r];
        const int o1 = s_off[r + 4];
        const int o2 = s_off[r + 8];
        const int o3 = s_off[r + 12];
        const float4 v0 = *(const float4*)(wbase + o0);
        const float4 v1 = *(const float4*)(wbase + o1);
        const float4 v2 = *(const float4*)(wbase + o2);
        const float4 v3 = *(const float4*)(wbase + o3);
        ax += (v0.x + v1.x) + (v2.x + v3.x);
        ay += (v0.y + v1.y) + (v2.y + v3.y);
        az += (v0.z + v1.z) + (v2.z + v3.z);
        aw += (v0.w + v1.w) + (v2.w + v3.w);
    }
    for (; r < end; r += 4) {
        const float4 v = *(const float4*)(wbase + s_off[r]);
        ax += v.x; ay += v.y; az += v.z; aw += v.w;
    }

    // Reduce across the 4 row-groups (lanes l16, l16+16, l16+32, l16+48).
    ax += __shfl_xor(ax, 16); ay += __shfl_xor(ay, 16);
    az += __shfl_xor(az, 16); aw += __shfl_xor(aw, 16);
    ax += __shfl_xor(ax, 32); ay += __shfl_xor(ay, 32);
    az += __shfl_xor(az, 32); aw += __shfl_xor(aw, 32);

    // Combine the two waves via LDS; wave 0 lanes 0-15 store the row.
    if (wave == 1 && lane < 16) {
        float4 p; p.x = ax; p.y = ay; p.z = az; p.w = aw;
        s_part[l16] = p;
    }
    __syncthreads();
    if (wave == 0 && lane < 16) {
        const float4 p = s_part[l16];
        const float inv = 1.f / (float)((len > 0) ? len : 1);
        float4 o;
        o.x = (ax + p.x) * inv;
        o.y = (ay + p.y) * inv;
        o.z = (az + p.z) * inv;
        o.w = (aw + p.w) * inv;
        *(float4*)(out + b * DIM + (l16 << 2)) = o;   // 256B coalesced store
    }
}

extern "C" void kernel_launch(void* const* d_in, const int* in_sizes, int n_in,
                              void* d_out, int out_size, void* d_ws, size_t ws_size,
                              hipStream_t stream) {
    const float* weight  = (const float*)d_in[0];
    const int*   idx     = (const int*)d_in[1];
    const int*   lengths = (const int*)d_in[2];
    float*       out     = (float*)d_out;

    hashbag_kernel<<<BAGS, 128, 0, stream>>>(weight, idx, lengths, out);
}